// Round 2
// baseline (360.043 us; speedup 1.0000x reference)
//
#include <hip/hip_runtime.h>

#define D 256

// ---------------- zero a byte region (float4 granular) ----------------

__global__ void zero_f4(float4* __restrict__ p, int n16) {
    int i = blockIdx.x * blockDim.x + threadIdx.x;
    if (i < n16) p[i] = make_float4(0.f, 0.f, 0.f, 0.f);
}

// ---------------- CSR build ----------------

__global__ void degree_kernel(const int* __restrict__ dst, int* __restrict__ deg, int E) {
    int e = blockIdx.x * blockDim.x + threadIdx.x;
    if (e < E) atomicAdd(&deg[dst[e]], 1);
}

// single-block exclusive scan over n<=16384 elements (n=10000 here)
__global__ __launch_bounds__(1024) void scan_kernel(const int* __restrict__ deg,
                                                    int* __restrict__ offsets,
                                                    int* __restrict__ cursor, int n) {
    const int CHUNK = 16;
    __shared__ int s[1024];
    int t = threadIdx.x;
    int base_idx = t * CHUNK;
    int vals[CHUNK];
    int local = 0;
#pragma unroll
    for (int i = 0; i < CHUNK; ++i) {
        int idx = base_idx + i;
        int v = (idx < n) ? deg[idx] : 0;
        vals[i] = v;
        local += v;
    }
    s[t] = local;
    __syncthreads();
    for (int off = 1; off < 1024; off <<= 1) {
        int v = (t >= off) ? s[t - off] : 0;
        __syncthreads();
        s[t] += v;
        __syncthreads();
    }
    int run = s[t] - local;
#pragma unroll
    for (int i = 0; i < CHUNK; ++i) {
        int idx = base_idx + i;
        if (idx < n) {
            offsets[idx] = run;
            cursor[idx]  = run;
            run += vals[i];
        }
    }
    if (t == 1023) offsets[n] = s[1023];
}

__global__ void bucket_kernel(const int* __restrict__ src, const int* __restrict__ dst,
                              int* __restrict__ cursor, int* __restrict__ csr, int E) {
    int e = blockIdx.x * blockDim.x + threadIdx.x;
    if (e < E) {
        int d = dst[e];
        int pos = atomicAdd(&cursor[d], 1);
        csr[pos] = src[e];
    }
}

// ---------------- aggregation: one wave per node, 4 rows in flight ----------------

__global__ __launch_bounds__(256) void agg_kernel(const float* __restrict__ x,
                                                  const int* __restrict__ csr,
                                                  const int* __restrict__ offsets,
                                                  float* __restrict__ agg, int M) {
    int node = (blockIdx.x * 256 + threadIdx.x) >> 6;
    int lane = threadIdx.x & 63;
    if (node >= M) return;
    int start = offsets[node];
    int end   = offsets[node + 1];
    float4 acc = {0.f, 0.f, 0.f, 0.f};
    int e = start;
    for (; e + 4 <= end; e += 4) {
        int s0 = csr[e + 0], s1 = csr[e + 1], s2 = csr[e + 2], s3 = csr[e + 3];
        float4 v0 = *(const float4*)&x[(long)s0 * D + lane * 4];
        float4 v1 = *(const float4*)&x[(long)s1 * D + lane * 4];
        float4 v2 = *(const float4*)&x[(long)s2 * D + lane * 4];
        float4 v3 = *(const float4*)&x[(long)s3 * D + lane * 4];
        acc.x += v0.x + v1.x + v2.x + v3.x;
        acc.y += v0.y + v1.y + v2.y + v3.y;
        acc.z += v0.z + v1.z + v2.z + v3.z;
        acc.w += v0.w + v1.w + v2.w + v3.w;
    }
    for (; e < end; ++e) {
        int s = csr[e];
        float4 v = *(const float4*)&x[(long)s * D + lane * 4];
        acc.x += v.x; acc.y += v.y; acc.z += v.z; acc.w += v.w;
    }
    int cnt = end - start;
    float sc = 1.0f / (float)(cnt > 0 ? cnt : 1);
    acc.x *= sc; acc.y *= sc; acc.z *= sc; acc.w *= sc;
    *(float4*)&agg[(long)node * D + lane * 4] = acc;
}

// ---------------- split-K fp32 GEMM, atomic accumulate ----------------
// C += A*B^T over chunk [kk0, kk0+KC). z = pass*CPP + chunk.
// A: [M,K] row-major, B: [N,K] row-major. C pre-zeroed; bias/relu in epilogue.

template <int BM, int BN, int BK, int TM, int TN>
__global__ __launch_bounds__((BM / TM) * (BN / TN))
void gemm_atomic(const float* __restrict__ A1, const float* __restrict__ B1,
                 const float* __restrict__ A2, const float* __restrict__ B2,
                 float* __restrict__ C, int M, int N, int K, int KC, int CPP) {
    constexpr int THREADS = (BM / TM) * (BN / TN);
    constexpr int TX = BN / TN;
    static_assert(THREADS == BM * (BK / 4), "one float4 per thread per tile");
    __shared__ float As[BK][BM + 4];
    __shared__ float Bs[BK][BN + 4];

    const int tid = threadIdx.x;
    const int tx = tid % TX;
    const int ty = tid / TX;
    const int m0 = blockIdx.x * BM;
    const int n0 = blockIdx.y * BN;
    const int pass = blockIdx.z / CPP;
    const int kk0  = (blockIdx.z % CPP) * KC;

    const float* __restrict__ A = pass ? A2 : A1;
    const float* __restrict__ B = pass ? B2 : B1;

    const int l_r = tid / (BK / 4);
    const int l_c = (tid % (BK / 4)) * 4;

    float acc[TM][TN] = {};

    for (int kk = kk0; kk < kk0 + KC; kk += BK) {
        {
            float4 v = {0.f, 0.f, 0.f, 0.f};
            int gm = m0 + l_r;
            if (gm < M) v = *(const float4*)&A[(long)gm * K + kk + l_c];
            As[l_c + 0][l_r] = v.x;
            As[l_c + 1][l_r] = v.y;
            As[l_c + 2][l_r] = v.z;
            As[l_c + 3][l_r] = v.w;
        }
        {
            float4 v = *(const float4*)&B[(long)(n0 + l_r) * K + kk + l_c];
            Bs[l_c + 0][l_r] = v.x;
            Bs[l_c + 1][l_r] = v.y;
            Bs[l_c + 2][l_r] = v.z;
            Bs[l_c + 3][l_r] = v.w;
        }
        __syncthreads();
#pragma unroll
        for (int k = 0; k < BK; ++k) {
            float4 a4 = *(const float4*)&As[k][ty * TM];
            float4 b4 = *(const float4*)&Bs[k][tx * TN];
            float a[4] = {a4.x, a4.y, a4.z, a4.w};
            float b[4] = {b4.x, b4.y, b4.z, b4.w};
#pragma unroll
            for (int i = 0; i < TM; ++i)
#pragma unroll
                for (int j = 0; j < TN; ++j) acc[i][j] = fmaf(a[i], b[j], acc[i][j]);
        }
        __syncthreads();
    }

#pragma unroll
    for (int i = 0; i < TM; ++i) {
        int gm = m0 + ty * TM + i;
        if (gm >= M) continue;
        float* crow = &C[(long)gm * N + n0 + tx * TN];
#pragma unroll
        for (int j = 0; j < TN; ++j) atomicAdd(&crow[j], acc[i][j]);
    }
}

// ---------------- epilogue: in-place h = relu(h + bias) ----------------

__global__ void bias_relu(float* __restrict__ h, const float* __restrict__ bias,
                          long total, int N) {
    long i4 = ((long)blockIdx.x * blockDim.x + threadIdx.x) * 4;
    if (i4 >= total) return;
    int col = (int)(i4 % N);
    float4 v = *(float4*)&h[i4];
    float4 b = *(const float4*)&bias[col];
    v.x = fmaxf(v.x + b.x, 0.f);
    v.y = fmaxf(v.y + b.y, 0.f);
    v.z = fmaxf(v.z + b.z, 0.f);
    v.w = fmaxf(v.w + b.w, 0.f);
    *(float4*)&h[i4] = v;
}

// ---------------- fused tail: h3[64] -> relu(W2)->32 -> W3 -> 3 ----------------

__global__ __launch_bounds__(256) void tail_kernel(const float* __restrict__ h3,
                                                   const float* __restrict__ W2,
                                                   const float* __restrict__ b2,
                                                   const float* __restrict__ W3,
                                                   const float* __restrict__ b3,
                                                   float* __restrict__ out, int M) {
    __shared__ float sW2[32 * 64];
    __shared__ float sW3[3 * 32];
    __shared__ float sb2[32];
    __shared__ float sb3[3];
    int t = threadIdx.x;
    for (int i = t; i < 32 * 64; i += 256) sW2[i] = W2[i];
    if (t < 96) sW3[t] = W3[t];
    if (t < 32) sb2[t] = b2[t];
    if (t < 3) sb3[t] = b3[t];
    __syncthreads();
    int m = blockIdx.x * 256 + t;
    if (m >= M) return;
    float r[64];
    const float4* hp = (const float4*)&h3[(long)m * 64];
#pragma unroll
    for (int i = 0; i < 16; ++i) {
        float4 v = hp[i];
        r[4 * i + 0] = v.x; r[4 * i + 1] = v.y; r[4 * i + 2] = v.z; r[4 * i + 3] = v.w;
    }
    float h4[32];
#pragma unroll
    for (int j = 0; j < 32; ++j) {
        float a = sb2[j];
#pragma unroll
        for (int k = 0; k < 64; ++k) a = fmaf(r[k], sW2[j * 64 + k], a);
        h4[j] = fmaxf(a, 0.f);
    }
#pragma unroll
    for (int j = 0; j < 3; ++j) {
        float a = sb3[j];
#pragma unroll
        for (int k = 0; k < 32; ++k) a = fmaf(h4[k], sW3[j * 32 + k], a);
        out[(long)m * 3 + j] = a;
    }
}

// ---------------- launch ----------------

extern "C" void kernel_launch(void* const* d_in, const int* in_sizes, int n_in,
                              void* d_out, int out_size, void* d_ws, size_t ws_size,
                              hipStream_t stream) {
    const float* x   = (const float*)d_in[0];
    const int*   ei  = (const int*)d_in[1];
    const float* W_l = (const float*)d_in[2];
    const float* b_l = (const float*)d_in[3];
    const float* W_r = (const float*)d_in[4];
    const float* Wa  = (const float*)d_in[5];
    const float* ba  = (const float*)d_in[6];
    const float* W1  = (const float*)d_in[7];
    const float* b1  = (const float*)d_in[8];
    const float* W2  = (const float*)d_in[9];
    const float* b2  = (const float*)d_in[10];
    const float* W3  = (const float*)d_in[11];
    const float* b3  = (const float*)d_in[12];
    float* out = (float*)d_out;

    const int M = in_sizes[0] / D;   // 10000
    const int E = in_sizes[1] / 2;   // 320000
    const int* src = ei;
    const int* dst = ei + E;

    // workspace carve. Zero-region first: [deg | h1 | h2 | h3]
    char* ws = (char*)d_ws;
    int*   deg = (int*)ws;     ws += 40064;                    // M*4 padded
    float* h1  = (float*)ws;   ws += (size_t)M * 256 * 4;      // 10.24 MB
    float* h2  = (float*)ws;   ws += (size_t)M * 128 * 4;      // 5.12 MB
    float* h3  = (float*)ws;   ws += (size_t)M * 64 * 4;       // 2.56 MB
    size_t zero_bytes = (char*)ws - (char*)d_ws;
    int*   offsets = (int*)ws; ws += 40064;
    int*   cursor  = (int*)ws; ws += 40064;
    int*   csr     = (int*)ws; ws += (size_t)E * 4;
    float* agg     = (float*)ws; ws += (size_t)M * 256 * 4;

    // 1. zero deg + h1 + h2 + h3 in one kernel
    int n16 = (int)(zero_bytes / 16);
    zero_f4<<<(n16 + 255) / 256, 256, 0, stream>>>((float4*)d_ws, n16);

    // 2. CSR build
    degree_kernel<<<(E + 255) / 256, 256, 0, stream>>>(dst, deg, E);
    scan_kernel<<<1, 1024, 0, stream>>>(deg, offsets, cursor, M);
    bucket_kernel<<<(E + 255) / 256, 256, 0, stream>>>(src, dst, cursor, csr, E);

    // 3. mean aggregation
    agg_kernel<<<(M + 3) / 4, 256, 0, stream>>>(x, csr, offsets, agg, M);

    const int MB = (M + 63) / 64;  // 157

    // 4. layer 1: h1 += agg@W_l^T (pass 0) + x@W_r^T (pass 1); grid.z = 2 passes
    gemm_atomic<64, 64, 16, 4, 4><<<dim3(MB, 4, 2), 256, 0, stream>>>(
        agg, W_l, x, W_r, h1, M, 256, 256, 256, 1);
    bias_relu<<<((M * 256 / 4) + 255) / 256, 256, 0, stream>>>(h1, b_l, (long)M * 256, 256);

    // 5. layer 2: h2 += h1@Wa^T, split-K=2 (KC=128)
    gemm_atomic<64, 64, 16, 4, 4><<<dim3(MB, 2, 2), 256, 0, stream>>>(
        h1, Wa, h1, Wa, h2, M, 128, 256, 128, 2);
    bias_relu<<<((M * 128 / 4) + 255) / 256, 256, 0, stream>>>(h2, ba, (long)M * 128, 128);

    // 6. layer 3: h3 += h2@W1^T, split-K=4 (KC=32)
    gemm_atomic<64, 64, 16, 4, 4><<<dim3(MB, 1, 4), 256, 0, stream>>>(
        h2, W1, h2, W1, h3, M, 64, 128, 32, 4);
    bias_relu<<<((M * 64 / 4) + 255) / 256, 256, 0, stream>>>(h3, b1, (long)M * 64, 64);

    // 7. layers 4+5 fused
    tail_kernel<<<(M + 255) / 256, 256, 0, stream>>>(h3, W2, b2, W3, b3, out, M);
}

// Round 3
// 312.377 us; speedup vs baseline: 1.1526x; 1.1526x over previous
//
#include <hip/hip_runtime.h>

#define D 256

// ---------------- small utils ----------------

__global__ void zero_int(int* __restrict__ p, int n) {
    int i = blockIdx.x * blockDim.x + threadIdx.x;
    if (i < n) p[i] = 0;
}

// ---------------- CSR build ----------------

__global__ void degree_kernel(const int* __restrict__ dst, int* __restrict__ deg, int E) {
    int e = blockIdx.x * blockDim.x + threadIdx.x;
    if (e < E) atomicAdd(&deg[dst[e]], 1);
}

// single-block exclusive scan over n<=16384 elements (n=10000 here)
__global__ __launch_bounds__(1024) void scan_kernel(const int* __restrict__ deg,
                                                    int* __restrict__ offsets,
                                                    int* __restrict__ cursor, int n) {
    const int CHUNK = 16;
    __shared__ int s[1024];
    int t = threadIdx.x;
    int base_idx = t * CHUNK;
    int vals[CHUNK];
    int local = 0;
#pragma unroll
    for (int i = 0; i < CHUNK; ++i) {
        int idx = base_idx + i;
        int v = (idx < n) ? deg[idx] : 0;
        vals[i] = v;
        local += v;
    }
    s[t] = local;
    __syncthreads();
    for (int off = 1; off < 1024; off <<= 1) {
        int v = (t >= off) ? s[t - off] : 0;
        __syncthreads();
        s[t] += v;
        __syncthreads();
    }
    int run = s[t] - local;
#pragma unroll
    for (int i = 0; i < CHUNK; ++i) {
        int idx = base_idx + i;
        if (idx < n) {
            offsets[idx] = run;
            cursor[idx]  = run;
            run += vals[i];
        }
    }
    if (t == 1023) offsets[n] = s[1023];
}

__global__ void bucket_kernel(const int* __restrict__ src, const int* __restrict__ dst,
                              int* __restrict__ cursor, int* __restrict__ csr, int E) {
    int e = blockIdx.x * blockDim.x + threadIdx.x;
    if (e < E) {
        int d = dst[e];
        int pos = atomicAdd(&cursor[d], 1);
        csr[pos] = src[e];
    }
}

// ---------------- aggregation: one wave per node, 4 rows in flight ----------------

__global__ __launch_bounds__(256) void agg_kernel(const float* __restrict__ x,
                                                  const int* __restrict__ csr,
                                                  const int* __restrict__ offsets,
                                                  float* __restrict__ agg, int M) {
    int node = (blockIdx.x * 256 + threadIdx.x) >> 6;
    int lane = threadIdx.x & 63;
    if (node >= M) return;
    int start = offsets[node];
    int end   = offsets[node + 1];
    float4 acc = {0.f, 0.f, 0.f, 0.f};
    int e = start;
    for (; e + 4 <= end; e += 4) {
        int s0 = csr[e + 0], s1 = csr[e + 1], s2 = csr[e + 2], s3 = csr[e + 3];
        float4 v0 = *(const float4*)&x[(long)s0 * D + lane * 4];
        float4 v1 = *(const float4*)&x[(long)s1 * D + lane * 4];
        float4 v2 = *(const float4*)&x[(long)s2 * D + lane * 4];
        float4 v3 = *(const float4*)&x[(long)s3 * D + lane * 4];
        acc.x += v0.x + v1.x + v2.x + v3.x;
        acc.y += v0.y + v1.y + v2.y + v3.y;
        acc.z += v0.z + v1.z + v2.z + v3.z;
        acc.w += v0.w + v1.w + v2.w + v3.w;
    }
    for (; e < end; ++e) {
        int s = csr[e];
        float4 v = *(const float4*)&x[(long)s * D + lane * 4];
        acc.x += v.x; acc.y += v.y; acc.z += v.z; acc.w += v.w;
    }
    int cnt = end - start;
    float sc = 1.0f / (float)(cnt > 0 ? cnt : 1);
    acc.x *= sc; acc.y *= sc; acc.z *= sc; acc.w *= sc;
    *(float4*)&agg[(long)node * D + lane * 4] = acc;
}

// ---------------- layer 1: h1 = relu(agg@W_l^T + x@W_r^T + b_l) ----------------
// BM=32, BN=64, BK=32, TM=4, TN=2, 256 threads. grid = (ceil(M/32), 4).

__global__ __launch_bounds__(256) void gemm1(const float* __restrict__ A1,
                                             const float* __restrict__ B1,
                                             const float* __restrict__ A2,
                                             const float* __restrict__ B2,
                                             const float* __restrict__ bias,
                                             float* __restrict__ C, int M) {
    __shared__ float sA[32][36];  // [k][m]
    __shared__ float sB[32][68];  // [k][n]

    const int tid = threadIdx.x;
    const int m0 = blockIdx.x * 32;
    const int n0 = blockIdx.y * 64;
    const int tx = tid & 31;   // col group: cols n0 + tx*2 .. +1
    const int ty = tid >> 5;   // row group: rows m0 + ty*4 .. +3
    const int l_r = tid >> 3;        // 0..31
    const int l_c = (tid & 7) * 4;   // 0,4,..,28

    float acc[4][2] = {};

    for (int pass = 0; pass < 2; ++pass) {
        const float* __restrict__ A = pass ? A2 : A1;
        const float* __restrict__ B = pass ? B2 : B1;
        for (int kk = 0; kk < 256; kk += 32) {
            // A tile: rows m0+l_r (guard), cols kk+l_c..+3
            {
                float4 v = {0.f, 0.f, 0.f, 0.f};
                int gm = m0 + l_r;
                if (gm < M) v = *(const float4*)&A[(long)gm * 256 + kk + l_c];
                sA[l_c + 0][l_r] = v.x;
                sA[l_c + 1][l_r] = v.y;
                sA[l_c + 2][l_r] = v.z;
                sA[l_c + 3][l_r] = v.w;
            }
            // B tile: rows n0+l_r and n0+l_r+32
            {
                float4 v = *(const float4*)&B[(long)(n0 + l_r) * 256 + kk + l_c];
                sB[l_c + 0][l_r] = v.x;
                sB[l_c + 1][l_r] = v.y;
                sB[l_c + 2][l_r] = v.z;
                sB[l_c + 3][l_r] = v.w;
                float4 w = *(const float4*)&B[(long)(n0 + l_r + 32) * 256 + kk + l_c];
                sB[l_c + 0][l_r + 32] = w.x;
                sB[l_c + 1][l_r + 32] = w.y;
                sB[l_c + 2][l_r + 32] = w.z;
                sB[l_c + 3][l_r + 32] = w.w;
            }
            __syncthreads();
#pragma unroll
            for (int k = 0; k < 32; ++k) {
                float4 a4 = *(const float4*)&sA[k][ty * 4];
                float2 b2 = *(const float2*)&sB[k][tx * 2];
                float a[4] = {a4.x, a4.y, a4.z, a4.w};
#pragma unroll
                for (int i = 0; i < 4; ++i) {
                    acc[i][0] = fmaf(a[i], b2.x, acc[i][0]);
                    acc[i][1] = fmaf(a[i], b2.y, acc[i][1]);
                }
            }
            __syncthreads();
        }
    }

    float2 bv = *(const float2*)&bias[n0 + tx * 2];
#pragma unroll
    for (int i = 0; i < 4; ++i) {
        int gm = m0 + ty * 4 + i;
        if (gm >= M) continue;
        float2 o;
        o.x = fmaxf(acc[i][0] + bv.x, 0.f);
        o.y = fmaxf(acc[i][1] + bv.y, 0.f);
        *(float2*)&C[(long)gm * 256 + n0 + tx * 2] = o;
    }
}

// ---------------- fused layers 2..5: one block owns 32 rows ----------------
// h2 = relu(h1@Wa^T + ba)   [*,128], K=256
// h3 = relu(h2@W1^T + b1)   [*,64],  K=128
// h4 = relu(h3@W2^T + b2)   [*,32],  K=64
// out = h4@W3^T + b3        [*,3],   K=32

__global__ __launch_bounds__(256) void mlp_fused(const float* __restrict__ h1,
                                                 const float* __restrict__ Wa,
                                                 const float* __restrict__ ba,
                                                 const float* __restrict__ W1,
                                                 const float* __restrict__ b1,
                                                 const float* __restrict__ W2,
                                                 const float* __restrict__ b2,
                                                 const float* __restrict__ W3,
                                                 const float* __restrict__ b3,
                                                 float* __restrict__ out, int M) {
    __shared__ float sA[32][260];   // h1 tile
    __shared__ float sH2[32][132];
    __shared__ float sH3[32][68];
    __shared__ float sH4[32][36];

    const int tid = threadIdx.x;
    const int r0 = blockIdx.x * 32;
    const int rg = tid >> 5;   // 0..7 -> rows rg*4..+3
    const int cg = tid & 31;

    // stage h1 tile (zeros for OOB rows)
    for (int i = tid; i < 2048; i += 256) {
        int row = i >> 6;
        int c = (i & 63) << 2;
        float4 v = {0.f, 0.f, 0.f, 0.f};
        if (r0 + row < M) v = *(const float4*)&h1[(long)(r0 + row) * 256 + c];
        *(float4*)&sA[row][c] = v;
    }
    __syncthreads();

    // ---- layer 2: 32x128, thread = 4 rows x 4 cols (cols cg*4..+3) ----
    {
        float4 bv = *(const float4*)&ba[cg * 4];
        float acc[4][4];
#pragma unroll
        for (int i = 0; i < 4; ++i) {
            acc[i][0] = bv.x; acc[i][1] = bv.y; acc[i][2] = bv.z; acc[i][3] = bv.w;
        }
        for (int k = 0; k < 256; k += 4) {
            float4 a[4], w[4];
#pragma unroll
            for (int i = 0; i < 4; ++i) a[i] = *(const float4*)&sA[rg * 4 + i][k];
#pragma unroll
            for (int j = 0; j < 4; ++j) w[j] = *(const float4*)&Wa[(long)(cg * 4 + j) * 256 + k];
#pragma unroll
            for (int i = 0; i < 4; ++i)
#pragma unroll
                for (int j = 0; j < 4; ++j) {
                    acc[i][j] = fmaf(a[i].x, w[j].x, acc[i][j]);
                    acc[i][j] = fmaf(a[i].y, w[j].y, acc[i][j]);
                    acc[i][j] = fmaf(a[i].z, w[j].z, acc[i][j]);
                    acc[i][j] = fmaf(a[i].w, w[j].w, acc[i][j]);
                }
        }
#pragma unroll
        for (int i = 0; i < 4; ++i) {
            float4 o;
            o.x = fmaxf(acc[i][0], 0.f);
            o.y = fmaxf(acc[i][1], 0.f);
            o.z = fmaxf(acc[i][2], 0.f);
            o.w = fmaxf(acc[i][3], 0.f);
            *(float4*)&sH2[rg * 4 + i][cg * 4] = o;
        }
    }
    __syncthreads();

    // ---- layer 3: 32x64, thread = 4 rows x 2 cols (cols cg*2..+1) ----
    {
        float acc[4][2];
#pragma unroll
        for (int i = 0; i < 4; ++i) {
            acc[i][0] = b1[cg * 2];
            acc[i][1] = b1[cg * 2 + 1];
        }
        for (int k = 0; k < 128; k += 4) {
            float4 a[4], w[2];
#pragma unroll
            for (int i = 0; i < 4; ++i) a[i] = *(const float4*)&sH2[rg * 4 + i][k];
#pragma unroll
            for (int j = 0; j < 2; ++j) w[j] = *(const float4*)&W1[(long)(cg * 2 + j) * 128 + k];
#pragma unroll
            for (int i = 0; i < 4; ++i)
#pragma unroll
                for (int j = 0; j < 2; ++j) {
                    acc[i][j] = fmaf(a[i].x, w[j].x, acc[i][j]);
                    acc[i][j] = fmaf(a[i].y, w[j].y, acc[i][j]);
                    acc[i][j] = fmaf(a[i].z, w[j].z, acc[i][j]);
                    acc[i][j] = fmaf(a[i].w, w[j].w, acc[i][j]);
                }
        }
#pragma unroll
        for (int i = 0; i < 4; ++i) {
            float2 o;
            o.x = fmaxf(acc[i][0], 0.f);
            o.y = fmaxf(acc[i][1], 0.f);
            *(float2*)&sH3[rg * 4 + i][cg * 2] = o;
        }
    }
    __syncthreads();

    // ---- layer 4: 32x32, thread = 4 rows x 1 col (col cg) ----
    {
        float acc[4];
#pragma unroll
        for (int i = 0; i < 4; ++i) acc[i] = b2[cg];
        for (int k = 0; k < 64; k += 4) {
            float4 w = *(const float4*)&W2[(long)cg * 64 + k];
#pragma unroll
            for (int i = 0; i < 4; ++i) {
                float4 a = *(const float4*)&sH3[rg * 4 + i][k];
                acc[i] = fmaf(a.x, w.x, acc[i]);
                acc[i] = fmaf(a.y, w.y, acc[i]);
                acc[i] = fmaf(a.z, w.z, acc[i]);
                acc[i] = fmaf(a.w, w.w, acc[i]);
            }
        }
#pragma unroll
        for (int i = 0; i < 4; ++i) sH4[rg * 4 + i][cg] = fmaxf(acc[i], 0.f);
    }
    __syncthreads();

    // ---- layer 5: 32x3, threads 0..95 ----
    if (tid < 96) {
        int row = tid / 3;
        int col = tid - row * 3;
        float acc = b3[col];
        for (int k = 0; k < 32; k += 4) {
            float4 a = *(const float4*)&sH4[row][k];
            float4 w = *(const float4*)&W3[(long)col * 32 + k];
            acc = fmaf(a.x, w.x, acc);
            acc = fmaf(a.y, w.y, acc);
            acc = fmaf(a.z, w.z, acc);
            acc = fmaf(a.w, w.w, acc);
        }
        if (r0 + row < M) out[(long)(r0 + row) * 3 + col] = acc;
    }
}

// ---------------- launch ----------------

extern "C" void kernel_launch(void* const* d_in, const int* in_sizes, int n_in,
                              void* d_out, int out_size, void* d_ws, size_t ws_size,
                              hipStream_t stream) {
    const float* x   = (const float*)d_in[0];
    const int*   ei  = (const int*)d_in[1];
    const float* W_l = (const float*)d_in[2];
    const float* b_l = (const float*)d_in[3];
    const float* W_r = (const float*)d_in[4];
    const float* Wa  = (const float*)d_in[5];
    const float* ba  = (const float*)d_in[6];
    const float* W1  = (const float*)d_in[7];
    const float* b1  = (const float*)d_in[8];
    const float* W2  = (const float*)d_in[9];
    const float* b2  = (const float*)d_in[10];
    const float* W3  = (const float*)d_in[11];
    const float* b3  = (const float*)d_in[12];
    float* out = (float*)d_out;

    const int M = in_sizes[0] / D;   // 10000
    const int E = in_sizes[1] / 2;   // 320000
    const int* src = ei;
    const int* dst = ei + E;

    // workspace carve (16B aligned chunks)
    char* ws = (char*)d_ws;
    int*   deg     = (int*)ws;   ws += 40064;
    int*   offsets = (int*)ws;   ws += 40064;
    int*   cursor  = (int*)ws;   ws += 40064;
    int*   csr     = (int*)ws;   ws += (size_t)E * 4;
    float* agg     = (float*)ws; ws += (size_t)M * 256 * 4;
    float* h1      = (float*)ws; ws += (size_t)M * 256 * 4;

    // CSR build
    zero_int<<<(M + 255) / 256, 256, 0, stream>>>(deg, M);
    degree_kernel<<<(E + 255) / 256, 256, 0, stream>>>(dst, deg, E);
    scan_kernel<<<1, 1024, 0, stream>>>(deg, offsets, cursor, M);
    bucket_kernel<<<(E + 255) / 256, 256, 0, stream>>>(src, dst, cursor, csr, E);

    // mean aggregation
    agg_kernel<<<(M + 3) / 4, 256, 0, stream>>>(x, csr, offsets, agg, M);

    // layer 1: h1 = relu(agg@W_l^T + x@W_r^T + b_l)
    gemm1<<<dim3((M + 31) / 32, 4), 256, 0, stream>>>(agg, W_l, x, W_r, b_l, h1, M);

    // layers 2..5 fused
    mlp_fused<<<(M + 31) / 32, 256, 0, stream>>>(h1, Wa, ba, W1, b1, W2, b2, W3, b3, out, M);
}